// Round 2
// baseline (382.378 us; speedup 1.0000x reference)
//
#include <hip/hip_runtime.h>
#include <stdint.h>

#define S_ROWS 100000
#define NQ     2048
#define M_POS  16
#define VOCABS 32
#define NWORD  64     // 32-query words covering all 2048 queries
#define NBLK   250    // blocks; each owns RPB support rows
#define RPB    400    // rows per block
#define RITER  16     // rows decoded+scored per iteration (one per wave)
#define KITER  25     // RPB / RITER
#define TPB    1024

// full adder / half adder on bit-planes
__device__ __forceinline__ void FA(uint32_t a, uint32_t b, uint32_t c,
                                   uint32_t& s, uint32_t& co) {
    uint32_t x = a ^ b;
    s  = x ^ c;
    co = (a & b) | (x & c);
}
__device__ __forceinline__ void HA(uint32_t a, uint32_t b, uint32_t& s, uint32_t& co) {
    s = a ^ b; co = a & b;
}

// decode one support row (one-hot floats, 512 per row) held in this wave's
// f0/f1 regs into 16 token bytes (pre-scaled by 8), written to LDS.
// lane covers floats [lane*8 .. lane*8+7]; 4 lanes per position.
__device__ __forceinline__ void decode_row(float4 f0, float4 f1, int lane,
                                           uint8_t* __restrict__ dst) {
    float base = (float)((lane & 3) * 64);
    float v = f0.x * (base + 0.f)  + f0.y * (base + 8.f)  + f0.z * (base + 16.f) + f0.w * (base + 24.f)
            + f1.x * (base + 32.f) + f1.y * (base + 40.f) + f1.z * (base + 48.f) + f1.w * (base + 56.f);
    v += __shfl_xor(v, 1);
    v += __shfl_xor(v, 2);
    if ((lane & 3) == 0) dst[lane >> 2] = (uint8_t)(v + 0.5f);
}

// ---------------- fused kernel: decode + bit-sliced match-count + argmax -------
// 250 blocks x 1024 threads, 1 block/CU (128 KB LDS table).
// Each block: 400 support rows x all 2048 queries.
//  - table[(m*32+v)*64 + w]: query bitmask, w in 0..63 -> gathers are
//    consecutive-address per wave (row is wave-uniform) => conflict-free.
//  - per iteration: 16 waves decode 16 rows (HBM, double-buffered 256 B token
//    LDS) while all 1024 threads score the previous 16 rows (LDS gathers + CSA).
//    HBM read of support (204.8 MB total) overlaps the LDS/VALU scoring.
__global__ __launch_bounds__(TPB, 4) void knn_fused(const int* __restrict__ utts,
                                                    const float* __restrict__ support,
                                                    uint32_t* __restrict__ best) {
    __shared__ uint32_t smem[M_POS * VOCABS * NWORD];   // 32768 words = 128 KB
    __shared__ __align__(16) uint8_t tokbuf[2][RITER * 16];  // 2 x 256 B

    const int t    = threadIdx.x;
    const int c    = blockIdx.x;
    const int r0   = c * RPB;
    const int w    = t & 63;        // word (also lane id within wave)
    const int sub  = t >> 6;        // wave id 0..15 (uniform per wave)
    const int lane = t & 63;

    // ---- zero table ----
    #pragma unroll
    for (int i = 0; i < 32; ++i) smem[t + 1024 * i] = 0u;
    __syncthreads();

    // ---- build query-bitmask table: bit j of table[(m*32+v)*64 + wb] = (utts[m][wb*32+j]==v)
    #pragma unroll
    for (int qq = 0; qq < 2; ++qq) {
        int q  = t + qq * 1024;
        int wb = q >> 5, j = q & 31;
        #pragma unroll
        for (int m = 0; m < M_POS; ++m) {
            int v = utts[m * NQ + q];
            atomicOr(&smem[(m * VOCABS + v) * NWORD + wb], 1u << j);
        }
    }

    // ---- prologue: load+decode iter 0, issue load for iter 1 ----
    const float4* gp = (const float4*)(support + (size_t)(r0 + sub) * 512) + lane * 2;
    float4 f0 = gp[0];
    float4 f1 = gp[1];
    gp += 2048;                       // advance 16 rows (16*128 float4)
    decode_row(f0, f1, lane, &tokbuf[0][sub * 16]);
    f0 = gp[0];
    f1 = gp[1];
    gp += 2048;
    __syncthreads();                  // table built + tokbuf[0] ready

    uint32_t cp0=0,cp1=0,cp2=0,cp3=0,cp4=0;   // current-max count planes
    uint32_t k0p=0,k1p=0,k2p=0,k3p=0,k4p=0;   // winning-iteration planes
    const uint32_t* tw = smem + w;

    #pragma unroll 5
    for (int i = 0; i < KITER; ++i) {
        // ---- score 16 rows of iter i: this thread handles (row=sub, word=w) ----
        uint4 ta = *(const uint4*)&tokbuf[i & 1][sub * 16];   // broadcast read
        uint32_t b[16];
        // index = m*2048 + v*64 + w ; byte holds v*8 -> (byte<<3)
        b[0]  = tw[ (ta.x        & 0xFFu) * 8 +  0*2048];
        b[1]  = tw[((ta.x >> 8)  & 0xFFu) * 8 +  1*2048];
        b[2]  = tw[((ta.x >> 16) & 0xFFu) * 8 +  2*2048];
        b[3]  = tw[((ta.x >> 24)        ) * 8 +  3*2048];
        b[4]  = tw[ (ta.y        & 0xFFu) * 8 +  4*2048];
        b[5]  = tw[((ta.y >> 8)  & 0xFFu) * 8 +  5*2048];
        b[6]  = tw[((ta.y >> 16) & 0xFFu) * 8 +  6*2048];
        b[7]  = tw[((ta.y >> 24)        ) * 8 +  7*2048];
        b[8]  = tw[ (ta.z        & 0xFFu) * 8 +  8*2048];
        b[9]  = tw[((ta.z >> 8)  & 0xFFu) * 8 +  9*2048];
        b[10] = tw[((ta.z >> 16) & 0xFFu) * 8 + 10*2048];
        b[11] = tw[((ta.z >> 24)        ) * 8 + 11*2048];
        b[12] = tw[ (ta.w        & 0xFFu) * 8 + 12*2048];
        b[13] = tw[((ta.w >> 8)  & 0xFFu) * 8 + 13*2048];
        b[14] = tw[((ta.w >> 16) & 0xFFu) * 8 + 14*2048];
        b[15] = tw[((ta.w >> 24)        ) * 8 + 15*2048];

        // CSA tree: 16 one-bit planes -> 5-bit count planes n0..n4
        uint32_t s10,s11,s12,s13,s14, c10,c11,c12,c13,c14;
        FA(b[0],b[1],b[2],   s10,c10);
        FA(b[3],b[4],b[5],   s11,c11);
        FA(b[6],b[7],b[8],   s12,c12);
        FA(b[9],b[10],b[11], s13,c13);
        FA(b[12],b[13],b[14],s14,c14);
        uint32_t s2a,c2a,s2b,c2b;
        FA(s10,s11,s12, s2a,c2a);
        FA(s13,s14,b[15], s2b,c2b);
        uint32_t n0,h0;  HA(s2a,s2b, n0,h0);
        uint32_t u,cu,vv,cv,x2,cx,n1,cy;
        FA(c10,c11,c12, u,cu);
        FA(c13,c14,c2a, vv,cv);
        FA(u,vv,c2b,    x2,cx);
        HA(x2,h0,       n1,cy);
        uint32_t y4,cz,n2,cw,n3,n4;
        FA(cu,cv,cx, y4,cz);
        HA(y4,cy,    n2,cw);
        HA(cz,cw,    n3,n4);

        // gt = (new count > current max), 5-bit unsigned, bit-sliced
        uint32_t eq = ~(n4 ^ cp4);
        uint32_t gt = n4 & ~cp4;
        gt |= eq & (n3 & ~cp3);  eq &= ~(n3 ^ cp3);
        gt |= eq & (n2 & ~cp2);  eq &= ~(n2 ^ cp2);
        gt |= eq & (n1 & ~cp1);  eq &= ~(n1 ^ cp1);
        gt |= eq & (n0 & ~cp0);

        uint32_t ng = ~gt;
        cp0 = (gt & n0) | (ng & cp0);
        cp1 = (gt & n1) | (ng & cp1);
        cp2 = (gt & n2) | (ng & cp2);
        cp3 = (gt & n3) | (ng & cp3);
        cp4 = (gt & n4) | (ng & cp4);
        // winning-iteration planes: wave-uniform SALU masks of i's bits
        uint32_t kb0 = 0u - (uint32_t)( i       & 1);
        uint32_t kb1 = 0u - (uint32_t)((i >> 1) & 1);
        uint32_t kb2 = 0u - (uint32_t)((i >> 2) & 1);
        uint32_t kb3 = 0u - (uint32_t)((i >> 3) & 1);
        uint32_t kb4 = 0u - (uint32_t)((i >> 4) & 1);
        k0p = (k0p & ng) | (gt & kb0);
        k1p = (k1p & ng) | (gt & kb1);
        k2p = (k2p & ng) | (gt & kb2);
        k3p = (k3p & ng) | (gt & kb3);
        k4p = (k4p & ng) | (gt & kb4);

        // ---- decode iter i+1 into the other token buffer; issue loads i+2 ----
        if (i + 1 < KITER) {
            decode_row(f0, f1, lane, &tokbuf[(i + 1) & 1][sub * 16]);
            if (i + 2 < KITER) {
                f0 = gp[0];
                f1 = gp[1];
                gp += 2048;
            }
        }
        __syncthreads();   // tokbuf[(i+1)&1] ready; all reads of tokbuf[i&1] done
    }
    // loop's final sync also fences last table gathers before keys overwrite smem

    // ---- extract per-query packed keys into LDS (swizzled, conflict-free) ----
    // key = (cnt << 17) | (0x1FFFF - idx); idx = r0 + i*16 + sub
    {
        uint32_t C  = 0x1FFFFu - (uint32_t)(r0 + sub);
        int       wp = (w + sub) & 63;            // swizzle: bank = (w+sub)&31
        #pragma unroll
        for (int j = 0; j < 32; ++j) {
            uint32_t cnt = ((cp0>>j)&1u) | (((cp1>>j)&1u)<<1) | (((cp2>>j)&1u)<<2)
                         | (((cp3>>j)&1u)<<3) | (((cp4>>j)&1u)<<4);
            uint32_t kk  = ((k0p>>j)&1u) | (((k1p>>j)&1u)<<1) | (((k2p>>j)&1u)<<2)
                         | (((k3p>>j)&1u)<<3) | (((k4p>>j)&1u)<<4);
            uint32_t key = (cnt << 17) + C - (kk << 4);
            smem[j * 1024 + sub * 64 + wp] = key;
        }
    }
    __syncthreads();

    // ---- reduce over 16 subs per (word, bit), then one atomicMax per query ----
    {
        int w2 = t & 63;
        #pragma unroll
        for (int jj = 0; jj < 2; ++jj) {
            int j2 = (t >> 6) * 2 + jj;
            uint32_t bestv = 0;
            #pragma unroll
            for (int s = 0; s < 16; ++s) {
                uint32_t v = smem[j2 * 1024 + s * 64 + ((w2 + s) & 63)];
                bestv = bestv > v ? bestv : v;
            }
            atomicMax(&best[w2 * 32 + j2], bestv);
        }
    }
}

// ---------------- output kernel: one-hot from best[] ---------------------------
__global__ __launch_bounds__(256) void knn_out(const uint32_t* __restrict__ best,
                                               const int* __restrict__ meanings,
                                               float* __restrict__ out) {
    int q = blockIdx.x * 256 + threadIdx.x;
    if (q >= NQ) return;
    uint32_t b = best[q];
    int idx = 0x1FFFF - (int)(b & 0x1FFFFu);
    float* o = out + (size_t)q * 50;
    #pragma unroll
    for (int tt = 0; tt < 5; ++tt) {
        int mv = meanings[(size_t)idx * 5 + tt];
        #pragma unroll
        for (int mm = 0; mm < 10; ++mm) o[tt * 10 + mm] = (mm == mv) ? 1.0f : 0.0f;
    }
}

extern "C" void kernel_launch(void* const* d_in, const int* in_sizes, int n_in,
                              void* d_out, int out_size, void* d_ws, size_t ws_size,
                              hipStream_t stream) {
    const int*   utts     = (const int*)d_in[0];     // [16, 2048]
    const float* support  = (const float*)d_in[1];   // [100000, 512]
    const int*   meanings = (const int*)d_in[2];     // [100000, 5]
    float* out = (float*)d_out;                      // [2048, 5, 10]

    uint32_t* best = (uint32_t*)d_ws;                // 8 KB

    hipMemsetAsync(best, 0, NQ * sizeof(uint32_t), stream);
    knn_fused<<<NBLK, TPB, 0, stream>>>(utts, support, best);
    knn_out<<<NQ / 256, 256, 0, stream>>>(best, meanings, out);
}